// Round 20
// baseline (45.044 us; speedup 1.0000x reference)
//
#include <hip/hip_runtime.h>
#include <hip/hip_bf16.h>
#include <math.h>

#define NP 16
#define NB 512
#define ND 2048
#define NM (NP*NB)          // 8192 rows
#define BM 128
#define BN 128
#define BK 128              // 128 k-elems = 128 BYTES per row per step (fp8)
#define NS (ND/BK)          // 16 K-steps
#define NCB (NB/BN)         // 4 col-blocks

typedef __attribute__((ext_vector_type(4))) float f32x4;
typedef unsigned int u32;

__device__ inline float dot4(float4 v) {
    return v.x * v.x + v.y * v.y + v.z * v.z + v.w * v.w;
}

// ---- f32x4 -> 4 packed OCP e4m3fn bytes (HW cvt; RNE, saturating) --------
#if __has_builtin(__builtin_amdgcn_cvt_pk_fp8_f32)
__device__ inline u32 pack4_fp8(float a, float b, float c, float d) {
    int w = 0;
    w = __builtin_amdgcn_cvt_pk_fp8_f32(a, b, w, false);  // bytes 0,1
    w = __builtin_amdgcn_cvt_pk_fp8_f32(c, d, w, true);   // bytes 2,3
    return (u32)w;
}
#else
#include <hip/hip_fp8.h>
__device__ inline u32 pack4_fp8(float a, float b, float c, float d) {
    u32 w  = (u32)__hip_cvt_float_to_fp8(a, __HIP_SATFINITE, __HIP_E4M3);
    w |= (u32)__hip_cvt_float_to_fp8(b, __HIP_SATFINITE, __HIP_E4M3) << 8;
    w |= (u32)__hip_cvt_float_to_fp8(c, __HIP_SATFINITE, __HIP_E4M3) << 16;
    w |= (u32)__hip_cvt_float_to_fp8(d, __HIP_SATFINITE, __HIP_E4M3) << 24;
    return w;
}
#endif

// ---------------------------------------------------------------------------
// Prep (d-sliced, R14-verified, unchanged).
__global__ __launch_bounds__(512) void prep_kernel(
        const float* __restrict__ feat,
        unsigned char* __restrict__ an,      // [NM][ND] fp8, row-normalized
        unsigned char* __restrict__ zn,      // [NB][ND] fp8, row-normalized
        float* __restrict__ accg, u32* __restrict__ cntr) {
    const int b = blockIdx.x, tid = threadIdx.x;
    const int lane = tid & 63, wv = tid >> 6;
    if (b == 0 && tid == 0) { accg[0] = 0.f; cntr[0] = 0u; }

    const int dbase = wv * 256 + lane * 4;           // float index within row
    const float4* fp4 = (const float4*)feat;

    float4 rv[16];
    float4 z = make_float4(0.f, 0.f, 0.f, 0.f);
#pragma unroll
    for (int p = 0; p < NP; ++p) {
        rv[p] = fp4[((size_t)(p * NB + b) * ND + dbase) >> 2];
        z.x += rv[p].x; z.y += rv[p].y; z.z += rv[p].z; z.w += rv[p].w;
    }

    __shared__ float sm_ssq[NP][8];
    __shared__ float sm_z[8];
    __shared__ float sm_inv[NP + 1];
#pragma unroll
    for (int p = 0; p < NP; ++p) {
        float ss = dot4(rv[p]);
#pragma unroll
        for (int off = 32; off > 0; off >>= 1) ss += __shfl_xor(ss, off);
        if (lane == 0) sm_ssq[p][wv] = ss;
    }
    {
        float zs = dot4(z);
#pragma unroll
        for (int off = 32; off > 0; off >>= 1) zs += __shfl_xor(zs, off);
        if (lane == 0) sm_z[wv] = zs;
    }
    __syncthreads();
    if (tid < NP) {
        float t = 0.f;
#pragma unroll
        for (int v = 0; v < 8; ++v) t += sm_ssq[tid][v];
        sm_inv[tid] = 1.f / fmaxf(sqrtf(t), 1e-12f);
    } else if (tid == NP) {
        float t = 0.f;
#pragma unroll
        for (int v = 0; v < 8; ++v) t += sm_z[v];
        sm_inv[NP] = 1.f / fmaxf(sqrtf(t), 1e-12f);
    }
    __syncthreads();

#pragma unroll
    for (int p = 0; p < NP; ++p) {
        const float inv = sm_inv[p];
        ((u32*)(an + (size_t)(p * NB + b) * ND))[dbase >> 2] =
            pack4_fp8(rv[p].x * inv, rv[p].y * inv, rv[p].z * inv, rv[p].w * inv);
    }
    const float iz = sm_inv[NP];
    ((u32*)(zn + (size_t)b * ND))[dbase >> 2] =
        pack4_fp8(z.x * iz, z.y * iz, z.z * iz, z.w * iz);
}

// ---------------------------------------------------------------------------
// GEMM + partial CE loss, fp8 e4m3. R19 schedule (read -> stage -> MFMA,
// runtime rotation, ONE barrier + counted vmcnt/step, XCD-affinity remap,
// max-free softmax, BK=128 conflict-free swizzle) at BM=128 / 8 waves /
// FOUR LDS buffers (128 KB, 1 block/CU). Stage(s+3) targets the buffer read
// at step s-1 — all waves passed barrier s after those reads, so one barrier
// per step still guarantees overwrite safety, with ~2 steps of DMA slack.
// Per-wave work identical to R19 (32x64 tile, acc[2][4]).
__global__ __launch_bounds__(512, 1) void gemm_loss_kernel(
        const unsigned char* __restrict__ an, // [NM][ND] fp8
        const unsigned char* __restrict__ zn, // [NB][ND] fp8
        float* __restrict__ psum_g,           // [NCB][NM]
        float* __restrict__ ppos_g) {         // [NM]
    __shared__ __align__(16) unsigned char abuf[4 * BM * BK];  // 4 x 16 KB
    __shared__ __align__(16) unsigned char bbuf[4 * BN * BK];  // 4 x 16 KB
    __shared__ float sm_sum[BM][2];
    __shared__ float sm_pos[BM];

    const int tid  = threadIdx.x;
    const int lane = tid & 63;
    const int w    = tid >> 6;       // 0..7
    const int wr   = w >> 1;         // row strip 0..3 (32 rows each)
    const int wc   = w & 1;          // col strip 0..1 (64 cols each)
    const int l15  = lane & 15;
    const int l4   = lane >> 4;      // 0..3
    // XCD-affinity remap: all 4 cb's of a row-panel share an XCD.
    const int xcd    = blockIdx.x & 7;
    const int slot   = blockIdx.x >> 3;          // 0..31
    const int cb     = slot & 3;
    const int rowblk = xcd + 8 * (slot >> 2);    // 0..63, bijective
    const int brow = rowblk * BM;
    const int bcol = cb * BN;

    f32x4 acc[2][4] = {};

    // Staging: 128 rows x 8 granules of 16B = 1024 chunks per operand;
    // 512 threads -> 2 chunks each (rows +0,+64). Swizzle cs = c ^ (r&7);
    // row offsets are multiples of 64 so one swizzle constant per thread.
    const int sr  = tid >> 3;                        // base row 0..63
    const int scs = (tid & 7) ^ (sr & 7);            // swizzled granule
    const unsigned char* asrc = an + (size_t)(brow + sr) * ND + scs * 16;
    const unsigned char* bsrc = zn + (size_t)(bcol + sr) * ND + scs * 16;

#define STAGE(BI, S) do {                                                     \
        const int koB_ = (S) * BK;                                            \
        __builtin_amdgcn_global_load_lds((const u32*)(asrc + koB_),           \
            (u32*)(&abuf[(BI) * 16384 + tid * 16]), 16, 0, 0);                \
        __builtin_amdgcn_global_load_lds((const u32*)(asrc + 64 * ND + koB_), \
            (u32*)(&abuf[(BI) * 16384 + 8192 + tid * 16]), 16, 0, 0);         \
        __builtin_amdgcn_global_load_lds((const u32*)(bsrc + koB_),           \
            (u32*)(&bbuf[(BI) * 16384 + tid * 16]), 16, 0, 0);                \
        __builtin_amdgcn_global_load_lds((const u32*)(bsrc + 64 * ND + koB_), \
            (u32*)(&bbuf[(BI) * 16384 + 8192 + tid * 16]), 16, 0, 0);         \
    } while (0)

    STAGE(0, 0);
    STAGE(1, 1);
    STAGE(2, 2);

    int acur = 0, astg = 3;
    for (int s = 0; s < NS; ++s) {
        // need buf s%4 complete; stages s+1, s+2 may stay in flight (4 ld ea)
        if (s + 2 < NS)      asm volatile("s_waitcnt vmcnt(8)" ::: "memory");
        else if (s + 1 < NS) asm volatile("s_waitcnt vmcnt(4)" ::: "memory");
        else                 asm volatile("s_waitcnt vmcnt(0)" ::: "memory");
        __builtin_amdgcn_sched_barrier(0);
        __builtin_amdgcn_s_barrier();          // buf staged; prev reads retired
        __builtin_amdgcn_sched_barrier(0);

        // frag reads: 8B chunk kk = kc*4+l4 (kc 0..3) of a 128B row
        long long af[4][2], bf[4][4];
#pragma unroll
        for (int kc = 0; kc < 4; ++kc) {
            const int g16 = kc * 2 + (l4 >> 1);
            const int lo8 = (l4 & 1) * 8;
#pragma unroll
            for (int m = 0; m < 2; ++m) {
                int r = wr * 32 + m * 16 + l15;
                int g = g16 ^ (r & 7);
                af[kc][m] = *(const long long*)(
                    &abuf[acur * 16384 + r * BK + g * 16 + lo8]);
            }
#pragma unroll
            for (int n = 0; n < 4; ++n) {
                int r = wc * 64 + n * 16 + l15;
                int g = g16 ^ (r & 7);
                bf[kc][n] = *(const long long*)(
                    &bbuf[acur * 16384 + r * BK + g * 16 + lo8]);
            }
        }

        if (s + 3 < NS) STAGE(astg, s + 3);    // DMA flies under the MFMAs

        __builtin_amdgcn_s_setprio(1);
#pragma unroll
        for (int kc = 0; kc < 4; ++kc)
#pragma unroll
        for (int m = 0; m < 2; ++m)
#pragma unroll
        for (int n = 0; n < 4; ++n)
            acc[m][n] = __builtin_amdgcn_mfma_f32_16x16x32_fp8_fp8(
                af[kc][m], bf[kc][n], acc[m][n], 0, 0, 0);
        __builtin_amdgcn_s_setprio(0);

        acur = (acur + 1) & 3;
        astg = (astg + 1) & 3;
    }
#undef STAGE

    // ---- epilogue: MAX-FREE partial sum(exp(logit)) over 128 cols ----
    // |sim| <= ~1.03 -> |logit| <= 5.2 -> exp in [5e-3, 181]: no overflow.
#pragma unroll
    for (int m = 0; m < 2; ++m) {
#pragma unroll
        for (int r = 0; r < 4; ++r) {
            const int lrow = wr * 32 + m * 16 + l4 * 4 + r;   // local row 0..127
            float lg[4];
            float se = 0.f;
#pragma unroll
            for (int n = 0; n < 4; ++n) {
                lg[n] = acc[m][n][r] * 5.0f;                  // /TEMP
                se += __expf(lg[n]);
            }
            se += __shfl_xor(se, 1);
            se += __shfl_xor(se, 2);
            se += __shfl_xor(se, 4);
            se += __shfl_xor(se, 8);
            if (l15 == 0) sm_sum[lrow][wc] = se;
            const int posc = (brow + lrow) & (NB - 1);        // global row % 512
#pragma unroll
            for (int n = 0; n < 4; ++n)
                if (bcol + wc * 64 + n * 16 + l15 == posc) sm_pos[lrow] = lg[n];
        }
    }
    __syncthreads();

    if (tid < BM) {
        const int lrow = tid;
        const int grow = brow + lrow;
        psum_g[cb * NM + grow] = sm_sum[lrow][0] + sm_sum[lrow][1];
        if (((grow & (NB - 1)) >> 7) == cb) ppos_g[grow] = sm_pos[lrow];
    }
}

// ---------------------------------------------------------------------------
// Combine 4 col-block partials per row -> loss; last block writes d_out.
__global__ __launch_bounds__(256) void reduce_kernel(
        const float* __restrict__ psum_g, const float* __restrict__ ppos_g,
        float* __restrict__ acc_g, u32* __restrict__ counter,
        float* __restrict__ out) {
    const int row = blockIdx.x * 256 + threadIdx.x;   // 32 blocks x 256
    float tot = psum_g[row] + psum_g[NM + row]
              + psum_g[2 * NM + row] + psum_g[3 * NM + row];
    float term = __logf(tot) - ppos_g[row];
#pragma unroll
    for (int off = 32; off > 0; off >>= 1) term += __shfl_xor(term, off);
    __shared__ float wsum[4];
    const int lane = threadIdx.x & 63, wv = threadIdx.x >> 6;
    if (lane == 0) wsum[wv] = term;
    __syncthreads();
    if (threadIdx.x == 0) {
        atomicAdd(acc_g, wsum[0] + wsum[1] + wsum[2] + wsum[3]);
        __threadfence();
        u32 old = atomicAdd(counter, 1u);
        if (old == 31u) {                       // last block: all adds visible
            float total = atomicAdd(acc_g, 0.0f);
            out[0] = total * (1.0f / (float)NM);
        }
    }
}

extern "C" void kernel_launch(void* const* d_in, const int* in_sizes, int n_in,
                              void* d_out, int out_size, void* d_ws, size_t ws_size,
                              hipStream_t stream) {
    const float* feat = (const float*)d_in[0];

    unsigned char* an = (unsigned char*)d_ws;              // 16 MB fp8
    unsigned char* zn = an + (size_t)NM * ND;              // 1 MB fp8
    float* psum = (float*)(zn + (size_t)NB * ND);          // NCB*NM
    float* ppos = psum + NCB * NM;                         // NM
    float* accg = ppos + NM;                               // 1 float
    u32*   cntr = (u32*)(accg + 1);                        // 1 u32

    prep_kernel<<<NB, 512, 0, stream>>>(feat, an, zn, accg, cntr);
    gemm_loss_kernel<<<(NM / BM) * NCB, 512, 0, stream>>>(an, zn, psum, ppos);
    reduce_kernel<<<NM / 256, 256, 0, stream>>>(psum, ppos, accg, cntr,
                                                (float*)d_out);
}

// Round 21
// 43.676 us; speedup vs baseline: 1.0313x; 1.0313x over previous
//
#include <hip/hip_runtime.h>
#include <hip/hip_bf16.h>
#include <math.h>

#define NP 16
#define NB 512
#define ND 2048
#define NM (NP*NB)          // 8192 rows
#define BM 64
#define BN 128
#define BK 128              // 128 k-elems = 128 BYTES per row per step (fp8)
#define NS (ND/BK)          // 16 K-steps
#define NCB (NB/BN)         // 4 col-blocks

typedef __attribute__((ext_vector_type(4))) float f32x4;
typedef unsigned int u32;

__device__ inline float dot4(float4 v) {
    return v.x * v.x + v.y * v.y + v.z * v.z + v.w * v.w;
}

// ---- f32x4 -> 4 packed OCP e4m3fn bytes (HW cvt; RNE, saturating) --------
#if __has_builtin(__builtin_amdgcn_cvt_pk_fp8_f32)
__device__ inline u32 pack4_fp8(float a, float b, float c, float d) {
    int w = 0;
    w = __builtin_amdgcn_cvt_pk_fp8_f32(a, b, w, false);  // bytes 0,1
    w = __builtin_amdgcn_cvt_pk_fp8_f32(c, d, w, true);   // bytes 2,3
    return (u32)w;
}
#else
#include <hip/hip_fp8.h>
__device__ inline u32 pack4_fp8(float a, float b, float c, float d) {
    u32 w  = (u32)__hip_cvt_float_to_fp8(a, __HIP_SATFINITE, __HIP_E4M3);
    w |= (u32)__hip_cvt_float_to_fp8(b, __HIP_SATFINITE, __HIP_E4M3) << 8;
    w |= (u32)__hip_cvt_float_to_fp8(c, __HIP_SATFINITE, __HIP_E4M3) << 16;
    w |= (u32)__hip_cvt_float_to_fp8(d, __HIP_SATFINITE, __HIP_E4M3) << 24;
    return w;
}
#endif

// ---------------------------------------------------------------------------
// Prep (d-sliced, R14-verified, unchanged).
__global__ __launch_bounds__(512) void prep_kernel(
        const float* __restrict__ feat,
        unsigned char* __restrict__ an,      // [NM][ND] fp8, row-normalized
        unsigned char* __restrict__ zn,      // [NB][ND] fp8, row-normalized
        float* __restrict__ accg, u32* __restrict__ cntr) {
    const int b = blockIdx.x, tid = threadIdx.x;
    const int lane = tid & 63, wv = tid >> 6;
    if (b == 0 && tid == 0) { accg[0] = 0.f; cntr[0] = 0u; }

    const int dbase = wv * 256 + lane * 4;           // float index within row
    const float4* fp4 = (const float4*)feat;

    float4 rv[16];
    float4 z = make_float4(0.f, 0.f, 0.f, 0.f);
#pragma unroll
    for (int p = 0; p < NP; ++p) {
        rv[p] = fp4[((size_t)(p * NB + b) * ND + dbase) >> 2];
        z.x += rv[p].x; z.y += rv[p].y; z.z += rv[p].z; z.w += rv[p].w;
    }

    __shared__ float sm_ssq[NP][8];
    __shared__ float sm_z[8];
    __shared__ float sm_inv[NP + 1];
#pragma unroll
    for (int p = 0; p < NP; ++p) {
        float ss = dot4(rv[p]);
#pragma unroll
        for (int off = 32; off > 0; off >>= 1) ss += __shfl_xor(ss, off);
        if (lane == 0) sm_ssq[p][wv] = ss;
    }
    {
        float zs = dot4(z);
#pragma unroll
        for (int off = 32; off > 0; off >>= 1) zs += __shfl_xor(zs, off);
        if (lane == 0) sm_z[wv] = zs;
    }
    __syncthreads();
    if (tid < NP) {
        float t = 0.f;
#pragma unroll
        for (int v = 0; v < 8; ++v) t += sm_ssq[tid][v];
        sm_inv[tid] = 1.f / fmaxf(sqrtf(t), 1e-12f);
    } else if (tid == NP) {
        float t = 0.f;
#pragma unroll
        for (int v = 0; v < 8; ++v) t += sm_z[v];
        sm_inv[NP] = 1.f / fmaxf(sqrtf(t), 1e-12f);
    }
    __syncthreads();

#pragma unroll
    for (int p = 0; p < NP; ++p) {
        const float inv = sm_inv[p];
        ((u32*)(an + (size_t)(p * NB + b) * ND))[dbase >> 2] =
            pack4_fp8(rv[p].x * inv, rv[p].y * inv, rv[p].z * inv, rv[p].w * inv);
    }
    const float iz = sm_inv[NP];
    ((u32*)(zn + (size_t)b * ND))[dbase >> 2] =
        pack4_fp8(z.x * iz, z.y * iz, z.z * iz, z.w * iz);
}

// ---------------------------------------------------------------------------
// GEMM + partial CE loss, fp8 e4m3 — R19-verified optimum. Block = 64x128,
// 256 thr = 4 waves (2x2), wave tile 32x64 (acc[2][4]), 2 blocks/CU.
// BK=128: 128 B rows = conflict-free LDS (row = exactly 32 banks; swizzle
// c ^= r&7 on 16B granules, same involution on stage-source and read).
// 3 LDS buffers, 2-deep staging, ONE barrier + counted vmcnt(6)/step,
// XCD-affinity remap, max-free softmax partials.
__global__ __launch_bounds__(256, 2) void gemm_loss_kernel(
        const unsigned char* __restrict__ an, // [NM][ND] fp8
        const unsigned char* __restrict__ zn, // [NB][ND] fp8
        float* __restrict__ psum_g,           // [NCB][NM]
        float* __restrict__ ppos_g) {         // [NM]
    __shared__ __align__(16) unsigned char abuf[3 * BM * BK];  // 3 x 8 KB
    __shared__ __align__(16) unsigned char bbuf[3 * BN * BK];  // 3 x 16 KB
    __shared__ float sm_sum[BM][2];
    __shared__ float sm_pos[BM];

    const int tid  = threadIdx.x;
    const int lane = tid & 63;
    const int w    = tid >> 6;       // 0..3
    const int wr   = w >> 1;         // row strip 0..1 (32 rows each)
    const int wc   = w & 1;          // col strip 0..1 (64 cols each)
    const int l15  = lane & 15;
    const int l4   = lane >> 4;      // 0..3
    // XCD-affinity remap (R18-verified): all 4 cb's of a row-panel share XCD.
    const int xcd    = blockIdx.x & 7;
    const int slot   = blockIdx.x >> 3;          // 0..63
    const int cb     = slot & 3;
    const int rowblk = xcd + 8 * (slot >> 2);    // 0..127, bijective
    const int brow = rowblk * BM;
    const int bcol = cb * BN;

    f32x4 acc[2][4] = {};

    const int sr  = tid >> 3;                        // base row 0..31
    const int scs = (tid & 7) ^ (sr & 7);            // swizzled granule
    const unsigned char* asrc = an + (size_t)(brow + sr) * ND + scs * 16;
    const unsigned char* bsrc = zn + (size_t)(bcol + sr) * ND + scs * 16;

#define STAGE(BI, S) do {                                                     \
        const int koB_ = (S) * BK;                                            \
        __builtin_amdgcn_global_load_lds((const u32*)(asrc + koB_),           \
            (u32*)(&abuf[(BI) * 8192 + tid * 16]), 16, 0, 0);                 \
        __builtin_amdgcn_global_load_lds((const u32*)(asrc + 32 * ND + koB_), \
            (u32*)(&abuf[(BI) * 8192 + 4096 + tid * 16]), 16, 0, 0);          \
        _Pragma("unroll")                                                     \
        for (int i = 0; i < 4; ++i) {                                         \
            __builtin_amdgcn_global_load_lds(                                 \
                (const u32*)(bsrc + (size_t)(32 * i) * ND + koB_),            \
                (u32*)(&bbuf[(BI) * 16384 + i * 4096 + tid * 16]), 16, 0, 0); \
        }                                                                     \
    } while (0)

    STAGE(0, 0);
    STAGE(1, 1);

    int acur = 0, astg = 2;
    for (int s = 0; s < NS; ++s) {
        if (s + 1 < NS) asm volatile("s_waitcnt vmcnt(6)" ::: "memory");
        else            asm volatile("s_waitcnt vmcnt(0)" ::: "memory");
        __builtin_amdgcn_sched_barrier(0);
        __builtin_amdgcn_s_barrier();          // buf staged by ALL waves;
        __builtin_amdgcn_sched_barrier(0);     // prev-step reads all retired

        // frag reads: 8B chunk kk = kc*4+l4 (kc 0..3) of a 128B row;
        // 16B granule g = kc*2 + (l4>>1) ^ (r&7), low half (l4&1)*8.
        long long af[4][2], bf[4][4];
#pragma unroll
        for (int kc = 0; kc < 4; ++kc) {
            const int g16 = kc * 2 + (l4 >> 1);
            const int lo8 = (l4 & 1) * 8;
#pragma unroll
            for (int m = 0; m < 2; ++m) {
                int r = wr * 32 + m * 16 + l15;
                int g = g16 ^ (r & 7);
                af[kc][m] = *(const long long*)(
                    &abuf[acur * 8192 + r * BK + g * 16 + lo8]);
            }
#pragma unroll
            for (int n = 0; n < 4; ++n) {
                int r = wc * 64 + n * 16 + l15;
                int g = g16 ^ (r & 7);
                bf[kc][n] = *(const long long*)(
                    &bbuf[acur * 16384 + r * BK + g * 16 + lo8]);
            }
        }

        if (s + 2 < NS) STAGE(astg, s + 2);    // DMA flies under the MFMAs

        __builtin_amdgcn_s_setprio(1);
#pragma unroll
        for (int kc = 0; kc < 4; ++kc)
#pragma unroll
        for (int m = 0; m < 2; ++m)
#pragma unroll
        for (int n = 0; n < 4; ++n)
            acc[m][n] = __builtin_amdgcn_mfma_f32_16x16x32_fp8_fp8(
                af[kc][m], bf[kc][n], acc[m][n], 0, 0, 0);
        __builtin_amdgcn_s_setprio(0);

        acur = (acur == 2) ? 0 : acur + 1;
        astg = (astg == 2) ? 0 : astg + 1;
    }
#undef STAGE

    // ---- epilogue: MAX-FREE partial sum(exp(logit)) over 128 cols ----
    // |sim| <= ~1.03 -> |logit| <= 5.2 -> exp in [5e-3, 181]: no overflow.
#pragma unroll
    for (int m = 0; m < 2; ++m) {
#pragma unroll
        for (int r = 0; r < 4; ++r) {
            const int lrow = wr * 32 + m * 16 + l4 * 4 + r;   // local row 0..63
            float lg[4];
            float se = 0.f;
#pragma unroll
            for (int n = 0; n < 4; ++n) {
                lg[n] = acc[m][n][r] * 5.0f;                  // /TEMP
                se += __expf(lg[n]);
            }
            se += __shfl_xor(se, 1);
            se += __shfl_xor(se, 2);
            se += __shfl_xor(se, 4);
            se += __shfl_xor(se, 8);
            if (l15 == 0) sm_sum[lrow][wc] = se;
            const int posc = (brow + lrow) & (NB - 1);        // global row % 512
#pragma unroll
            for (int n = 0; n < 4; ++n)
                if (bcol + wc * 64 + n * 16 + l15 == posc) sm_pos[lrow] = lg[n];
        }
    }
    __syncthreads();

    if (tid < BM) {
        const int lrow = tid;
        const int grow = brow + lrow;
        psum_g[cb * NM + grow] = sm_sum[lrow][0] + sm_sum[lrow][1];
        if (((grow & (NB - 1)) >> 7) == cb) ppos_g[grow] = sm_pos[lrow];
    }
}

// ---------------------------------------------------------------------------
// Combine 4 col-block partials per row -> loss; last block writes d_out.
__global__ __launch_bounds__(256) void reduce_kernel(
        const float* __restrict__ psum_g, const float* __restrict__ ppos_g,
        float* __restrict__ acc_g, u32* __restrict__ counter,
        float* __restrict__ out) {
    const int row = blockIdx.x * 256 + threadIdx.x;   // 32 blocks x 256
    float tot = psum_g[row] + psum_g[NM + row]
              + psum_g[2 * NM + row] + psum_g[3 * NM + row];
    float term = __logf(tot) - ppos_g[row];
#pragma unroll
    for (int off = 32; off > 0; off >>= 1) term += __shfl_xor(term, off);
    __shared__ float wsum[4];
    const int lane = threadIdx.x & 63, wv = threadIdx.x >> 6;
    if (lane == 0) wsum[wv] = term;
    __syncthreads();
    if (threadIdx.x == 0) {
        atomicAdd(acc_g, wsum[0] + wsum[1] + wsum[2] + wsum[3]);
        __threadfence();
        u32 old = atomicAdd(counter, 1u);
        if (old == 31u) {                       // last block: all adds visible
            float total = atomicAdd(acc_g, 0.0f);
            out[0] = total * (1.0f / (float)NM);
        }
    }
}

extern "C" void kernel_launch(void* const* d_in, const int* in_sizes, int n_in,
                              void* d_out, int out_size, void* d_ws, size_t ws_size,
                              hipStream_t stream) {
    const float* feat = (const float*)d_in[0];

    unsigned char* an = (unsigned char*)d_ws;              // 16 MB fp8
    unsigned char* zn = an + (size_t)NM * ND;              // 1 MB fp8
    float* psum = (float*)(zn + (size_t)NB * ND);          // NCB*NM
    float* ppos = psum + NCB * NM;                         // NM
    float* accg = ppos + NM;                               // 1 float
    u32*   cntr = (u32*)(accg + 1);                        // 1 u32

    prep_kernel<<<NB, 512, 0, stream>>>(feat, an, zn, accg, cntr);
    gemm_loss_kernel<<<(NM / BM) * NCB, 256, 0, stream>>>(an, zn, psum, ppos);
    reduce_kernel<<<NM / 256, 256, 0, stream>>>(psum, ppos, accg, cntr,
                                                (float*)d_out);
}